// Round 24
// baseline (476.871 us; speedup 1.0000x reference)
//
#include <hip/hip_runtime.h>
#include <hip/hip_bf16.h>
#include <math.h>

#define NNODES 50000
#define NEDGES 500000
#define NTILES 1563   // (NNODES+31)/32

__device__ __forceinline__ float lrelu(float x) { return x > 0.f ? x : 0.2f * x; }

__device__ __forceinline__ unsigned short f2bf(float f) {
    unsigned int u = __float_as_uint(f);
    u += 0x7FFFu + ((u >> 16) & 1u);   // round-nearest-even
    return (unsigned short)(u >> 16);
}

__device__ __forceinline__ float bf_lo(unsigned u) { return __uint_as_float(u << 16); }
__device__ __forceinline__ float bf_hi(unsigned u) { return __uint_as_float(u & 0xFFFF0000u); }

// ============ prep: fold the two GEMMs -- Wcomb = Wt@[WgO|WgS], wc1 = Wt@Wc, bcomb = bt@[WgO|WgS], c0 = bt.Wc ============
__global__ void wprep_kernel(const float* __restrict__ Wt0, const float* __restrict__ Wt1,
                             const float* __restrict__ Wt2,
                             const float* __restrict__ bt0, const float* __restrict__ bt1,
                             const float* __restrict__ bt2,
                             const float* __restrict__ WgO, const float* __restrict__ WgS,
                             const float* __restrict__ Wc,
                             float* __restrict__ Wcomb, float* __restrict__ wc1,
                             float* __restrict__ bcomb, float* __restrict__ c0) {
    __shared__ float wrow[128];
    const int b = blockIdx.x;   // 0..226
    const int t = threadIdx.x;  // 256
    const float* src;
    int isBias = 0, ty = 0, k = 0;
    if (b < 64)       { src = Wt0; k = b;       ty = 0; }
    else if (b < 96)  { src = Wt1; k = b - 64;  ty = 1; }
    else if (b < 224) { src = Wt2; k = b - 96;  ty = 2; }
    else              { isBias = 1; ty = b - 224; src = (ty == 0) ? bt0 : (ty == 1) ? bt1 : bt2; }
    if (t < 128) wrow[t] = isBias ? src[t] : src[k * 128 + t];
    __syncthreads();
    const float* Wg = (t < 128) ? WgO : WgS;
    const int j = t & 127;
    float acc = 0.f;
#pragma unroll 8
    for (int m = 0; m < 128; m++) acc += wrow[m] * Wg[m * 128 + j];
    if (isBias) bcomb[ty * 256 + t] = acc;
    else        Wcomb[b * 256 + t] = acc;
    if (t < 64) {   // wave 0: dot(wrow, Wc)
        float s = wrow[t] * Wc[t] + wrow[t + 64] * Wc[t + 64];
#pragma unroll
        for (int o = 32; o > 0; o >>= 1) s += __shfl_xor(s, o);
        if (t == 0) { if (isBias) c0[ty] = s; else wc1[b] = s; }
    }
}

// ============ batched fused kernel: xp = X@Wcomb + bcomb ; scores ; embPart = X.wc1 + c0 ============
__launch_bounds__(256)
__global__ void xp_all_b(const float* __restrict__ X0, const float* __restrict__ X1,
                         const float* __restrict__ X2,
                         const float* __restrict__ Wcomb, const float* __restrict__ wc1,
                         const float* __restrict__ bcomb, const float* __restrict__ c0,
                         const float* __restrict__ asO, const float* __restrict__ adO,
                         const float* __restrict__ asS, const float* __restrict__ adS,
                         float* __restrict__ embPart,
                         unsigned short* __restrict__ xpO, unsigned short* __restrict__ xpS,
                         float* __restrict__ ssO, float* __restrict__ sdO,
                         float* __restrict__ ssS, float* __restrict__ sdS, int n) {
    __shared__ float xs[32][128];
    const int t = threadIdx.x;
    const int j4 = t & 31, r = t >> 5;
    const int tile = blockIdx.x % NTILES;
    const int type = blockIdx.x / NTILES;
    const int row0 = tile * 32;

    const float* X;
    int K, ksh, off;
    if (type == 0)      { X = X0; K = 64;  ksh = 4; off = 0;  }
    else if (type == 1) { X = X1; K = 32;  ksh = 3; off = 64; }
    else                { X = X2; K = 128; ksh = 5; off = 96; }
    const size_t tb = (size_t)type * n;

    const int KQ = K >> 2;
    for (int f = t; f < 32 * KQ; f += 256) {
        int row = f >> ksh, kq = f & (KQ - 1);
        float4 v = {0.f, 0.f, 0.f, 0.f};
        if (row0 + row < n) v = *(const float4*)&X[(size_t)(row0 + row) * K + kq * 4];
        *(float4*)&xs[row][kq * 4] = v;
    }
    __syncthreads();

    // single GEMM: [aO|aS] = X @ Wcomb ; dp = X . wc1
    float4 aO[4], aS[4];
    float dp[4] = {0.f, 0.f, 0.f, 0.f};
#pragma unroll
    for (int p = 0; p < 4; p++) { aO[p] = {0.f, 0.f, 0.f, 0.f}; aS[p] = {0.f, 0.f, 0.f, 0.f}; }
    const float* wb = Wcomb + (size_t)off * 256;
    const float* w1p = wc1 + off;
#pragma unroll 4
    for (int k = 0; k < K; k++) {
        float4 wo = *(const float4*)&wb[k * 256 + j4 * 4];
        float4 ws = *(const float4*)&wb[k * 256 + 128 + j4 * 4];
        float w1 = w1p[k];
        float x0 = xs[r][k], x1 = xs[r + 8][k], x2 = xs[r + 16][k], x3 = xs[r + 24][k];
        aO[0].x += x0 * wo.x; aO[0].y += x0 * wo.y; aO[0].z += x0 * wo.z; aO[0].w += x0 * wo.w;
        aO[1].x += x1 * wo.x; aO[1].y += x1 * wo.y; aO[1].z += x1 * wo.z; aO[1].w += x1 * wo.w;
        aO[2].x += x2 * wo.x; aO[2].y += x2 * wo.y; aO[2].z += x2 * wo.z; aO[2].w += x2 * wo.w;
        aO[3].x += x3 * wo.x; aO[3].y += x3 * wo.y; aO[3].z += x3 * wo.z; aO[3].w += x3 * wo.w;
        aS[0].x += x0 * ws.x; aS[0].y += x0 * ws.y; aS[0].z += x0 * ws.z; aS[0].w += x0 * ws.w;
        aS[1].x += x1 * ws.x; aS[1].y += x1 * ws.y; aS[1].z += x1 * ws.z; aS[1].w += x1 * ws.w;
        aS[2].x += x2 * ws.x; aS[2].y += x2 * ws.y; aS[2].z += x2 * ws.z; aS[2].w += x2 * ws.w;
        aS[3].x += x3 * ws.x; aS[3].y += x3 * ws.y; aS[3].z += x3 * ws.z; aS[3].w += x3 * ws.w;
        dp[0] += x0 * w1; dp[1] += x1 * w1; dp[2] += x2 * w1; dp[3] += x3 * w1;
    }
    float4 bO = *(const float4*)&bcomb[type * 256 + j4 * 4];
    float4 bS = *(const float4*)&bcomb[type * 256 + 128 + j4 * 4];
    const float cc = c0[type];
#pragma unroll
    for (int p = 0; p < 4; p++) {
        aO[p].x += bO.x; aO[p].y += bO.y; aO[p].z += bO.z; aO[p].w += bO.w;
        aS[p].x += bS.x; aS[p].y += bS.y; aS[p].z += bS.z; aS[p].w += bS.w;
    }

    float4 vasO = *(const float4*)&asO[j4 * 4];
    float4 vadO = *(const float4*)&adO[j4 * 4];
    float4 vasS = *(const float4*)&asS[j4 * 4];
    float4 vadS = *(const float4*)&adS[j4 * 4];
#pragma unroll
    for (int p = 0; p < 4; p++) {
        int row = row0 + r + 8 * p;
        if (row < n) {
            ushort4 uo, us;
            uo.x = f2bf(aO[p].x); uo.y = f2bf(aO[p].y); uo.z = f2bf(aO[p].z); uo.w = f2bf(aO[p].w);
            us.x = f2bf(aS[p].x); us.y = f2bf(aS[p].y); us.z = f2bf(aS[p].z); us.w = f2bf(aS[p].w);
            *(ushort4*)&xpO[(tb + row) * 128 + j4 * 4] = uo;
            *(ushort4*)&xpS[(tb + row) * 128 + j4 * 4] = us;
            if (j4 == 0) embPart[tb + row] = dp[p] + cc;
        }
        float psO = aO[p].x * vasO.x + aO[p].y * vasO.y + aO[p].z * vasO.z + aO[p].w * vasO.w;
        float pdO = aO[p].x * vadO.x + aO[p].y * vadO.y + aO[p].z * vadO.z + aO[p].w * vadO.w;
        float psS = aS[p].x * vasS.x + aS[p].y * vasS.y + aS[p].z * vasS.z + aS[p].w * vasS.w;
        float pdS = aS[p].x * vadS.x + aS[p].y * vadS.y + aS[p].z * vadS.z + aS[p].w * vadS.w;
#pragma unroll
        for (int o = 4; o > 0; o >>= 1) {
            psO += __shfl_xor(psO, o);
            pdO += __shfl_xor(pdO, o);
            psS += __shfl_xor(psS, o);
            pdS += __shfl_xor(pdS, o);
        }
        if ((j4 & 7) == 0 && row < n) {
            size_t hidx = (tb + row) * 4 + (j4 >> 3);
            ssO[hidx] = psO; sdO[hidx] = pdO;
            ssS[hidx] = psS; sdS[hidx] = pdS;
        }
    }
}

// ============ CSR build, both edge types batched: counts2[2N], rp2[2N+1], cp2[2E] ============
__global__ void zero_int(int* __restrict__ p, int n) {
    int i = blockIdx.x * blockDim.x + threadIdx.x;
    if (i < n) p[i] = 0;
}

__global__ void count2_kernel(const int* __restrict__ eiO, const int* __restrict__ eiS,
                              int e, int n, int* __restrict__ counts2) {
    int q = blockIdx.x * blockDim.x + threadIdx.x;
    if (q >= 2 * e) return;
    int ty = q >= e;
    int i = ty ? q - e : q;
    const int* ei = ty ? eiS : eiO;
    atomicAdd(&counts2[ty * n + ei[e + i]], 1);
}

__global__ void block_sum_kernel(const int* __restrict__ counts, int n, int* __restrict__ psum) {
    __shared__ int ws[16];
    int tid = threadIdx.x, lane = tid & 63, wid = tid >> 6;
    int i = blockIdx.x * 1024 + tid;
    int v = (i < n) ? counts[i] : 0;
#pragma unroll
    for (int o = 1; o < 64; o <<= 1) v += __shfl_xor(v, o);
    if (lane == 0) ws[wid] = v;
    __syncthreads();
    if (tid < 16) {
        int s = ws[tid];
#pragma unroll
        for (int o = 1; o < 16; o <<= 1) s += __shfl_xor(s, o, 16);
        if (tid == 0) psum[blockIdx.x] = s;
    }
}

// single block, 128 threads, nb <= 128
__global__ void scan_psum_big(int* __restrict__ psum, int nb, int* __restrict__ total) {
    __shared__ int wsum[2];
    int tid = threadIdx.x, lane = tid & 63, wid = tid >> 6;
    int v = (tid < nb) ? psum[tid] : 0;
    int x = v;
#pragma unroll
    for (int o = 1; o < 64; o <<= 1) {
        int t = __shfl_up(x, o);
        if (lane >= o) x += t;
    }
    if (lane == 63) wsum[wid] = x;
    __syncthreads();
    int base = (wid == 1) ? wsum[0] : 0;
    if (tid < nb) psum[tid] = base + x - v;   // exclusive
    if (tid == 127) *total = wsum[0] + wsum[1];
}

__global__ void scan_block_kernel(const int* __restrict__ counts, const int* __restrict__ psum,
                                  int n, int* __restrict__ row_ptr, int* __restrict__ cursor) {
    __shared__ int ws[16];
    int tid = threadIdx.x, lane = tid & 63, wid = tid >> 6;
    int i = blockIdx.x * 1024 + tid;
    int v = (i < n) ? counts[i] : 0;
    int x = v;
#pragma unroll
    for (int o = 1; o < 64; o <<= 1) {
        int t = __shfl_up(x, o);
        if (lane >= o) x += t;
    }
    if (lane == 63) ws[wid] = x;
    __syncthreads();
    if (tid < 16) {
        int s = ws[tid];
#pragma unroll
        for (int o = 1; o < 16; o <<= 1) {
            int t = __shfl_up(s, o, 16);
            if (tid >= o) s += t;
        }
        ws[tid] = s;
    }
    __syncthreads();
    int base = psum[blockIdx.x] + (wid ? ws[wid - 1] : 0);
    int excl = base + x - v;
    if (i < n) { row_ptr[i] = excl; cursor[i] = excl; }
}

__global__ void scatter2_kernel(const int* __restrict__ eiO, const int* __restrict__ eiS,
                                int e, int n, int* __restrict__ cursor2,
                                long long* __restrict__ cp2) {
    int q = blockIdx.x * blockDim.x + threadIdx.x;
    if (q >= 2 * e) return;
    int ty = q >= e;
    int i = ty ? q - e : q;
    const int* ei = ty ? eiS : eiO;
    int d = ei[e + i];
    int p = atomicAdd(&cursor2[ty * n + d], 1);
    cp2[p] = ((long long)i << 32) | (unsigned)ei[i];
}

// canonicalize slot order per row -> deterministic CSR (2N rows)
__global__ void sort_rows_kernel(const int* __restrict__ rp, long long* __restrict__ cp, int n) {
    int i = blockIdx.x * blockDim.x + threadIdx.x;
    if (i >= n) return;
    int r0 = rp[i], r1 = rp[i + 1];
    for (int a = r0 + 1; a < r1; a++) {
        long long v = cp[a];
        int b = a - 1;
        while (b >= r0 && cp[b] > v) {
            cp[b + 1] = cp[b];
            b--;
        }
        cp[b + 1] = v;
    }
}

// ============ pass A: per-SLOT raw attention weights (all 3 types) -> al3 in CSR-slot order ============
__global__ void alpha_slot_kernel(const int* __restrict__ eiO, const int* __restrict__ eiS,
                                  const long long* __restrict__ cp2,
                                  const float* __restrict__ ssO, const float* __restrict__ sdO,
                                  const float* __restrict__ ssS, const float* __restrict__ sdS,
                                  float* __restrict__ al3, int e, int n) {
    int q = blockIdx.x * blockDim.x + threadIdx.x;
    if (q >= 2 * e) return;
    long long v = cp2[q];
    int s = (int)(v & 0xFFFFFFFFll), eid = (int)(v >> 32);
    int conv = q >= e;
    int d = (conv ? eiS : eiO)[e + eid];
    const float* ssb = conv ? ssS : ssO;
    const float* sdb = conv ? sdS : sdO;
#pragma unroll
    for (int ty = 0; ty < 3; ty++) {
        const float* ss = ssb + (size_t)ty * n * 4;
        const float* sd = sdb + (size_t)ty * n * 4;
        float4 svs = *(const float4*)&ss[s * 4];
        float4 svd = *(const float4*)&ss[d * 4];
        float4 dvd = *(const float4*)&sd[d * 4];
        float4 a;
        a.x = __expf(lrelu(svs.x + dvd.x) - lrelu(svd.x + dvd.x));
        a.y = __expf(lrelu(svs.y + dvd.y) - lrelu(svd.y + dvd.y));
        a.z = __expf(lrelu(svs.z + dvd.z) - lrelu(svd.z + dvd.z));
        a.w = __expf(lrelu(svs.w + dvd.w) - lrelu(svd.w + dvd.w));
        *(float4*)&al3[((size_t)ty * 2 * e + q) * 4] = a;
    }
}

// ============ pass B: wave per (type, node); conv-per-half, 4 ch/lane, 4-deep unrolled edge loop ============
__global__ void gat_fused_b(const unsigned short* __restrict__ xpO,
                            const unsigned short* __restrict__ xpS,
                            const float* __restrict__ al3,
                            const long long* __restrict__ cp2, const int* __restrict__ rp2,
                            const float* __restrict__ bgO, const float* __restrict__ bgS,
                            const float* __restrict__ embPart, const float* __restrict__ Wc,
                            const float* __restrict__ bc, float* __restrict__ out, int n) {
    const int wave = threadIdx.x >> 6, lane = threadIdx.x & 63;
    const int i3 = blockIdx.x * 4 + wave;
    if (i3 >= 3 * n) return;
    const int ty = i3 / n, i = i3 - ty * n;
    const int half = lane >> 5, l5 = lane & 31;
    const int ch0 = l5 * 4, hh = l5 >> 3;

    const unsigned short* myxp = (half ? xpS : xpO) + (size_t)ty * n * 128;
    const float* alB = al3 + (size_t)ty * 2 * NEDGES * 4;   // absolute slot index

    const int r0 = half ? rp2[n + i] : rp2[i];
    const int r1 = half ? rp2[n + i + 1] : rp2[i + 1];
    const int deg = r1 - r0;
    const int degOther = __shfl_xor(deg, 32);
    const int dmax = deg > degOther ? deg : degOther;

    float t = 0.f, o0 = 0.f, o1 = 0.f, o2 = 0.f, o3 = 0.f;
    for (int it = 0; it < dmax; it += 4) {
        int k0 = r0 + it;
        bool v0 = (it < deg), v1 = (it + 1 < deg), v2 = (it + 2 < deg), v3 = (it + 3 < deg);
        int k0c = v0 ? k0 : 0;
        int k1c = v1 ? k0 + 1 : 0;
        int k2c = v2 ? k0 + 2 : 0;
        int k3c = v3 ? k0 + 3 : 0;
        long long p0 = cp2[k0c], p1 = cp2[k1c], p2 = cp2[k2c], p3 = cp2[k3c];
        int s0 = (int)(p0 & 0xFFFFFFFFll), s1 = (int)(p1 & 0xFFFFFFFFll);
        int s2 = (int)(p2 & 0xFFFFFFFFll), s3 = (int)(p3 & 0xFFFFFFFFll);
        float a0 = v0 ? alB[(size_t)k0c * 4 + hh] : 0.f;
        float a1 = v1 ? alB[(size_t)k1c * 4 + hh] : 0.f;
        float a2 = v2 ? alB[(size_t)k2c * 4 + hh] : 0.f;
        float a3 = v3 ? alB[(size_t)k3c * 4 + hh] : 0.f;
        uint2 u0 = *(const uint2*)&myxp[(size_t)s0 * 128 + ch0];
        uint2 u1 = *(const uint2*)&myxp[(size_t)s1 * 128 + ch0];
        uint2 u2 = *(const uint2*)&myxp[(size_t)s2 * 128 + ch0];
        uint2 u3 = *(const uint2*)&myxp[(size_t)s3 * 128 + ch0];
        t += a0 + a1;
        t += a2 + a3;
        o0 += a0 * bf_lo(u0.x) + a1 * bf_lo(u1.x);
        o0 += a2 * bf_lo(u2.x) + a3 * bf_lo(u3.x);
        o1 += a0 * bf_hi(u0.x) + a1 * bf_hi(u1.x);
        o1 += a2 * bf_hi(u2.x) + a3 * bf_hi(u3.x);
        o2 += a0 * bf_lo(u0.y) + a1 * bf_lo(u1.y);
        o2 += a2 * bf_lo(u2.y) + a3 * bf_lo(u3.y);
        o3 += a0 * bf_hi(u0.y) + a1 * bf_hi(u1.y);
        o3 += a2 * bf_hi(u2.y) + a3 * bf_hi(u3.y);
    }
    {   // self-loop: raw alpha = exp(0) = 1
        uint2 u = *(const uint2*)&myxp[(size_t)i * 128 + ch0];
        o0 += bf_lo(u.x); o1 += bf_hi(u.x); o2 += bf_lo(u.y); o3 += bf_hi(u.y);
    }
    const float id = 1.f / (t + 1.f);
    float f0 = id * o0, f1 = id * o1, f2 = id * o2, f3 = id * o3;
    // merge conv halves: lane l and l^32 hold O/S for the same channels
    f0 += __shfl_xor(f0, 32);
    f1 += __shfl_xor(f1, 32);
    f2 += __shfl_xor(f2, 32);
    f3 += __shfl_xor(f3, 32);

    float4 b4O = *(const float4*)&bgO[ch0];
    float4 b4S = *(const float4*)&bgS[ch0];
    float4 w4 = *(const float4*)&Wc[ch0];
    float p = (f0 + b4O.x + b4S.x) * w4.x + (f1 + b4O.y + b4S.y) * w4.y
            + (f2 + b4O.z + b4S.z) * w4.z + (f3 + b4O.w + b4S.w) * w4.w;
#pragma unroll
    for (int o = 16; o > 0; o >>= 1) p += __shfl_xor(p, o);   // reduce within 32-lane half
    if (lane == 0) out[i3] = 1.f / (1.f + expf(-(p + embPart[i3] + bc[0])));
}

extern "C" void kernel_launch(void* const* d_in, const int* in_sizes, int n_in,
                              void* d_out, int out_size, void* d_ws, size_t ws_size,
                              hipStream_t stream) {
    const int N = NNODES, E = NEDGES;
    const float* x_acc = (const float*)d_in[0];
    const float* x_cus = (const float*)d_in[1];
    const float* x_txn = (const float*)d_in[2];
    const int* ei_owns = (const int*)d_in[4];
    const int* ei_shr = (const int*)d_in[5];
    const float* W_acc = (const float*)d_in[6];
    const float* b_acc = (const float*)d_in[7];
    const float* W_cus = (const float*)d_in[8];
    const float* b_cus = (const float*)d_in[9];
    const float* W_txn = (const float*)d_in[10];
    const float* b_txn = (const float*)d_in[11];
    const float* Wg_o = (const float*)d_in[12];
    const float* as_o = (const float*)d_in[13];
    const float* ad_o = (const float*)d_in[14];
    const float* bg_o = (const float*)d_in[15];
    const float* Wg_s = (const float*)d_in[16];
    const float* as_s = (const float*)d_in[17];
    const float* ad_s = (const float*)d_in[18];
    const float* bg_s = (const float*)d_in[19];
    const float* W_cls = (const float*)d_in[20];
    const float* b_cls = (const float*)d_in[21];
    float* out = (float*)d_out;

    float* wf = (float*)d_ws;
    int* iw = (int*)d_ws;
    // batched layout (all 3 types resident):
    unsigned short* xp_o3 = (unsigned short*)(wf + 0);          // 3N*128 bf16 = 9.6M f
    unsigned short* xp_s3 = (unsigned short*)(wf + 9600000);    // 9.6M f
    float* ss_o3 = wf + 19200000;                               // 3N*4 = 600k
    float* sd_o3 = wf + 19800000;
    float* ss_s3 = wf + 20400000;
    float* sd_s3 = wf + 21000000;
    float* al3   = wf + 21600000;                               // 3 * 2E * 4 = 12M (slot order)
    float* embPart = wf + 33600000;                             // 3N = 150k
    int* rp2    = iw + 33750008;                                // 2N+1
    long long* cp2 = (long long*)(iw + 33850016);               // 2E u64 (even int ofs)
    float* Wcomb = wf + 35850016;                               // 224*256 = 57344
    float* wc1   = wf + 35907360;                               // 224
    float* bcomb = wf + 35907584;                               // 3*256 = 768
    float* c0    = wf + 35908352;                               // 3
    // CSR scratch overlaps al3 region (dead until alpha_slot runs, after CSR completes):
    int* counts2 = (int*)al3;                                   // 2N
    int* cursor2 = counts2 + 100000;                            // 2N
    int* psum    = cursor2 + 100000;                            // 128

    const int gN2 = (2 * N + 255) / 256;
    const int gE2 = (2 * E + 255) / 256;
    const int gS2 = (2 * N + 1023) / 1024;  // 98 blocks
    const int gXP = 3 * NTILES;
    const int gA = (3 * N + 3) / 4;

    // prep: combined weights (fold embed GEMM into the xp GEMM)
    wprep_kernel<<<227, 256, 0, stream>>>(W_acc, W_cus, W_txn, b_acc, b_cus, b_txn,
                                          Wg_o, Wg_s, W_cls, Wcomb, wc1, bcomb, c0);

    // batched CSR for both edge types (src = row 0, dst = row 1); canonical slot order via sort
    zero_int<<<gN2, 256, 0, stream>>>(counts2, 2 * N);
    count2_kernel<<<gE2, 256, 0, stream>>>(ei_owns, ei_shr, E, N, counts2);
    block_sum_kernel<<<gS2, 1024, 0, stream>>>(counts2, 2 * N, psum);
    scan_psum_big<<<1, 128, 0, stream>>>(psum, gS2, rp2 + 2 * N);
    scan_block_kernel<<<gS2, 1024, 0, stream>>>(counts2, psum, 2 * N, rp2, cursor2);
    scatter2_kernel<<<gE2, 256, 0, stream>>>(ei_owns, ei_shr, E, N, cursor2, cp2);
    sort_rows_kernel<<<gN2, 256, 0, stream>>>(rp2, cp2, 2 * N);

    // batched: one xp launch -> one alpha launch (slot order) -> one aggregate launch
    xp_all_b<<<gXP, 256, 0, stream>>>(x_acc, x_cus, x_txn,
                                      Wcomb, wc1, bcomb, c0,
                                      as_o, ad_o, as_s, ad_s,
                                      embPart, xp_o3, xp_s3,
                                      ss_o3, sd_o3, ss_s3, sd_s3, N);
    alpha_slot_kernel<<<gE2, 256, 0, stream>>>(ei_owns, ei_shr, cp2,
                                               ss_o3, sd_o3, ss_s3, sd_s3,
                                               al3, E, N);
    gat_fused_b<<<gA, 256, 0, stream>>>(xp_o3, xp_s3, al3,
                                        cp2, rp2, bg_o, bg_s,
                                        embPart, W_cls, b_cls, out, N);
}

// Round 27
// 465.839 us; speedup vs baseline: 1.0237x; 1.0237x over previous
//
#include <hip/hip_runtime.h>
#include <hip/hip_bf16.h>
#include <math.h>

#define NNODES 50000
#define NEDGES 500000
#define NTILES 1563   // (NNODES+31)/32

__device__ __forceinline__ float lrelu(float x) { return x > 0.f ? x : 0.2f * x; }

__device__ __forceinline__ unsigned short f2bf(float f) {
    unsigned int u = __float_as_uint(f);
    u += 0x7FFFu + ((u >> 16) & 1u);   // round-nearest-even
    return (unsigned short)(u >> 16);
}

// ============ prep: fold the two GEMMs -- Wcomb = Wt@[WgO|WgS], wc1 = Wt@Wc, bcomb = bt@[WgO|WgS], c0 = bt.Wc ============
__global__ void wprep_kernel(const float* __restrict__ Wt0, const float* __restrict__ Wt1,
                             const float* __restrict__ Wt2,
                             const float* __restrict__ bt0, const float* __restrict__ bt1,
                             const float* __restrict__ bt2,
                             const float* __restrict__ WgO, const float* __restrict__ WgS,
                             const float* __restrict__ Wc,
                             float* __restrict__ Wcomb, float* __restrict__ wc1,
                             float* __restrict__ bcomb, float* __restrict__ c0) {
    __shared__ float wrow[128];
    const int b = blockIdx.x;   // 0..226
    const int t = threadIdx.x;  // 256
    const float* src;
    int isBias = 0, ty = 0, k = 0;
    if (b < 64)       { src = Wt0; k = b;       ty = 0; }
    else if (b < 96)  { src = Wt1; k = b - 64;  ty = 1; }
    else if (b < 224) { src = Wt2; k = b - 96;  ty = 2; }
    else              { isBias = 1; ty = b - 224; src = (ty == 0) ? bt0 : (ty == 1) ? bt1 : bt2; }
    if (t < 128) wrow[t] = isBias ? src[t] : src[k * 128 + t];
    __syncthreads();
    const float* Wg = (t < 128) ? WgO : WgS;
    const int j = t & 127;
    float acc = 0.f;
#pragma unroll 8
    for (int m = 0; m < 128; m++) acc += wrow[m] * Wg[m * 128 + j];
    if (isBias) bcomb[ty * 256 + t] = acc;
    else        Wcomb[b * 256 + t] = acc;
    if (t < 64) {   // wave 0: dot(wrow, Wc)
        float s = wrow[t] * Wc[t] + wrow[t + 64] * Wc[t + 64];
#pragma unroll
        for (int o = 32; o > 0; o >>= 1) s += __shfl_xor(s, o);
        if (t == 0) { if (isBias) c0[ty] = s; else wc1[b] = s; }
    }
}

// ============ batched fused kernel: xp = X@Wcomb + bcomb ; scores ; embPart = X.wc1 + c0 ============
__launch_bounds__(256)
__global__ void xp_all_b(const float* __restrict__ X0, const float* __restrict__ X1,
                         const float* __restrict__ X2,
                         const float* __restrict__ Wcomb, const float* __restrict__ wc1,
                         const float* __restrict__ bcomb, const float* __restrict__ c0,
                         const float* __restrict__ asO, const float* __restrict__ adO,
                         const float* __restrict__ asS, const float* __restrict__ adS,
                         float* __restrict__ embPart,
                         unsigned short* __restrict__ xpO, unsigned short* __restrict__ xpS,
                         float* __restrict__ ssO, float* __restrict__ sdO,
                         float* __restrict__ ssS, float* __restrict__ sdS, int n) {
    __shared__ float xs[32][128];
    const int t = threadIdx.x;
    const int j4 = t & 31, r = t >> 5;
    const int tile = blockIdx.x % NTILES;
    const int type = blockIdx.x / NTILES;
    const int row0 = tile * 32;

    const float* X;
    int K, ksh, off;
    if (type == 0)      { X = X0; K = 64;  ksh = 4; off = 0;  }
    else if (type == 1) { X = X1; K = 32;  ksh = 3; off = 64; }
    else                { X = X2; K = 128; ksh = 5; off = 96; }
    const size_t tb = (size_t)type * n;

    const int KQ = K >> 2;
    for (int f = t; f < 32 * KQ; f += 256) {
        int row = f >> ksh, kq = f & (KQ - 1);
        float4 v = {0.f, 0.f, 0.f, 0.f};
        if (row0 + row < n) v = *(const float4*)&X[(size_t)(row0 + row) * K + kq * 4];
        *(float4*)&xs[row][kq * 4] = v;
    }
    __syncthreads();

    // single GEMM: [aO|aS] = X @ Wcomb ; dp = X . wc1
    float4 aO[4], aS[4];
    float dp[4] = {0.f, 0.f, 0.f, 0.f};
#pragma unroll
    for (int p = 0; p < 4; p++) { aO[p] = {0.f, 0.f, 0.f, 0.f}; aS[p] = {0.f, 0.f, 0.f, 0.f}; }
    const float* wb = Wcomb + (size_t)off * 256;
    const float* w1p = wc1 + off;
#pragma unroll 4
    for (int k = 0; k < K; k++) {
        float4 wo = *(const float4*)&wb[k * 256 + j4 * 4];
        float4 ws = *(const float4*)&wb[k * 256 + 128 + j4 * 4];
        float w1 = w1p[k];
        float x0 = xs[r][k], x1 = xs[r + 8][k], x2 = xs[r + 16][k], x3 = xs[r + 24][k];
        aO[0].x += x0 * wo.x; aO[0].y += x0 * wo.y; aO[0].z += x0 * wo.z; aO[0].w += x0 * wo.w;
        aO[1].x += x1 * wo.x; aO[1].y += x1 * wo.y; aO[1].z += x1 * wo.z; aO[1].w += x1 * wo.w;
        aO[2].x += x2 * wo.x; aO[2].y += x2 * wo.y; aO[2].z += x2 * wo.z; aO[2].w += x2 * wo.w;
        aO[3].x += x3 * wo.x; aO[3].y += x3 * wo.y; aO[3].z += x3 * wo.z; aO[3].w += x3 * wo.w;
        aS[0].x += x0 * ws.x; aS[0].y += x0 * ws.y; aS[0].z += x0 * ws.z; aS[0].w += x0 * ws.w;
        aS[1].x += x1 * ws.x; aS[1].y += x1 * ws.y; aS[1].z += x1 * ws.z; aS[1].w += x1 * ws.w;
        aS[2].x += x2 * ws.x; aS[2].y += x2 * ws.y; aS[2].z += x2 * ws.z; aS[2].w += x2 * ws.w;
        aS[3].x += x3 * ws.x; aS[3].y += x3 * ws.y; aS[3].z += x3 * ws.z; aS[3].w += x3 * ws.w;
        dp[0] += x0 * w1; dp[1] += x1 * w1; dp[2] += x2 * w1; dp[3] += x3 * w1;
    }
    float4 bO = *(const float4*)&bcomb[type * 256 + j4 * 4];
    float4 bS = *(const float4*)&bcomb[type * 256 + 128 + j4 * 4];
    const float cc = c0[type];
#pragma unroll
    for (int p = 0; p < 4; p++) {
        aO[p].x += bO.x; aO[p].y += bO.y; aO[p].z += bO.z; aO[p].w += bO.w;
        aS[p].x += bS.x; aS[p].y += bS.y; aS[p].z += bS.z; aS[p].w += bS.w;
    }

    float4 vasO = *(const float4*)&asO[j4 * 4];
    float4 vadO = *(const float4*)&adO[j4 * 4];
    float4 vasS = *(const float4*)&asS[j4 * 4];
    float4 vadS = *(const float4*)&adS[j4 * 4];
#pragma unroll
    for (int p = 0; p < 4; p++) {
        int row = row0 + r + 8 * p;
        if (row < n) {
            ushort4 uo, us;
            uo.x = f2bf(aO[p].x); uo.y = f2bf(aO[p].y); uo.z = f2bf(aO[p].z); uo.w = f2bf(aO[p].w);
            us.x = f2bf(aS[p].x); us.y = f2bf(aS[p].y); us.z = f2bf(aS[p].z); us.w = f2bf(aS[p].w);
            *(ushort4*)&xpO[(tb + row) * 128 + j4 * 4] = uo;
            *(ushort4*)&xpS[(tb + row) * 128 + j4 * 4] = us;
            if (j4 == 0) embPart[tb + row] = dp[p] + cc;
        }
        float psO = aO[p].x * vasO.x + aO[p].y * vasO.y + aO[p].z * vasO.z + aO[p].w * vasO.w;
        float pdO = aO[p].x * vadO.x + aO[p].y * vadO.y + aO[p].z * vadO.z + aO[p].w * vadO.w;
        float psS = aS[p].x * vasS.x + aS[p].y * vasS.y + aS[p].z * vasS.z + aS[p].w * vasS.w;
        float pdS = aS[p].x * vadS.x + aS[p].y * vadS.y + aS[p].z * vadS.z + aS[p].w * vadS.w;
#pragma unroll
        for (int o = 4; o > 0; o >>= 1) {
            psO += __shfl_xor(psO, o);
            pdO += __shfl_xor(pdO, o);
            psS += __shfl_xor(psS, o);
            pdS += __shfl_xor(pdS, o);
        }
        if ((j4 & 7) == 0 && row < n) {
            size_t hidx = (tb + row) * 4 + (j4 >> 3);
            ssO[hidx] = psO; sdO[hidx] = pdO;
            ssS[hidx] = psS; sdS[hidx] = pdS;
        }
    }
}

// ============ CSR build, both edge types batched: counts2[2N], rp2[2N+1], cp2[2E] ============
__global__ void zero_int(int* __restrict__ p, int n) {
    int i = blockIdx.x * blockDim.x + threadIdx.x;
    if (i < n) p[i] = 0;
}

__global__ void count2_kernel(const int* __restrict__ eiO, const int* __restrict__ eiS,
                              int e, int n, int* __restrict__ counts2) {
    int q = blockIdx.x * blockDim.x + threadIdx.x;
    if (q >= 2 * e) return;
    int ty = q >= e;
    int i = ty ? q - e : q;
    const int* ei = ty ? eiS : eiO;
    atomicAdd(&counts2[ty * n + ei[e + i]], 1);
}

__global__ void block_sum_kernel(const int* __restrict__ counts, int n, int* __restrict__ psum) {
    __shared__ int ws[16];
    int tid = threadIdx.x, lane = tid & 63, wid = tid >> 6;
    int i = blockIdx.x * 1024 + tid;
    int v = (i < n) ? counts[i] : 0;
#pragma unroll
    for (int o = 1; o < 64; o <<= 1) v += __shfl_xor(v, o);
    if (lane == 0) ws[wid] = v;
    __syncthreads();
    if (tid < 16) {
        int s = ws[tid];
#pragma unroll
        for (int o = 1; o < 16; o <<= 1) s += __shfl_xor(s, o, 16);
        if (tid == 0) psum[blockIdx.x] = s;
    }
}

// single block, 128 threads, nb <= 128
__global__ void scan_psum_big(int* __restrict__ psum, int nb, int* __restrict__ total) {
    __shared__ int wsum[2];
    int tid = threadIdx.x, lane = tid & 63, wid = tid >> 6;
    int v = (tid < nb) ? psum[tid] : 0;
    int x = v;
#pragma unroll
    for (int o = 1; o < 64; o <<= 1) {
        int t = __shfl_up(x, o);
        if (lane >= o) x += t;
    }
    if (lane == 63) wsum[wid] = x;
    __syncthreads();
    int base = (wid == 1) ? wsum[0] : 0;
    if (tid < nb) psum[tid] = base + x - v;   // exclusive
    if (tid == 127) *total = wsum[0] + wsum[1];
}

__global__ void scan_block_kernel(const int* __restrict__ counts, const int* __restrict__ psum,
                                  int n, int* __restrict__ row_ptr, int* __restrict__ cursor) {
    __shared__ int ws[16];
    int tid = threadIdx.x, lane = tid & 63, wid = tid >> 6;
    int i = blockIdx.x * 1024 + tid;
    int v = (i < n) ? counts[i] : 0;
    int x = v;
#pragma unroll
    for (int o = 1; o < 64; o <<= 1) {
        int t = __shfl_up(x, o);
        if (lane >= o) x += t;
    }
    if (lane == 63) ws[wid] = x;
    __syncthreads();
    if (tid < 16) {
        int s = ws[tid];
#pragma unroll
        for (int o = 1; o < 16; o <<= 1) {
            int t = __shfl_up(s, o, 16);
            if (tid >= o) s += t;
        }
        ws[tid] = s;
    }
    __syncthreads();
    int base = psum[blockIdx.x] + (wid ? ws[wid - 1] : 0);
    int excl = base + x - v;
    if (i < n) { row_ptr[i] = excl; cursor[i] = excl; }
}

__global__ void scatter2_kernel(const int* __restrict__ eiO, const int* __restrict__ eiS,
                                int e, int n, int* __restrict__ cursor2,
                                long long* __restrict__ cp2) {
    int q = blockIdx.x * blockDim.x + threadIdx.x;
    if (q >= 2 * e) return;
    int ty = q >= e;
    int i = ty ? q - e : q;
    const int* ei = ty ? eiS : eiO;
    int d = ei[e + i];
    int p = atomicAdd(&cursor2[ty * n + d], 1);
    cp2[p] = ((long long)i << 32) | (unsigned)ei[i];
}

// canonicalize slot order per row -> deterministic CSR (2N rows)
__global__ void sort_rows_kernel(const int* __restrict__ rp, long long* __restrict__ cp, int n) {
    int i = blockIdx.x * blockDim.x + threadIdx.x;
    if (i >= n) return;
    int r0 = rp[i], r1 = rp[i + 1];
    for (int a = r0 + 1; a < r1; a++) {
        long long v = cp[a];
        int b = a - 1;
        while (b >= r0 && cp[b] > v) {
            cp[b + 1] = cp[b];
            b--;
        }
        cp[b + 1] = v;
    }
}

// ============ pass A: per-SLOT raw attention weights (all 3 types) -> al3 in CSR-slot order ============
__global__ void alpha_slot_kernel(const int* __restrict__ eiO, const int* __restrict__ eiS,
                                  const long long* __restrict__ cp2,
                                  const float* __restrict__ ssO, const float* __restrict__ sdO,
                                  const float* __restrict__ ssS, const float* __restrict__ sdS,
                                  float* __restrict__ al3, int e, int n) {
    int q = blockIdx.x * blockDim.x + threadIdx.x;
    if (q >= 2 * e) return;
    long long v = cp2[q];
    int s = (int)(v & 0xFFFFFFFFll), eid = (int)(v >> 32);
    int conv = q >= e;
    int d = (conv ? eiS : eiO)[e + eid];
    const float* ssb = conv ? ssS : ssO;
    const float* sdb = conv ? sdS : sdO;
#pragma unroll
    for (int ty = 0; ty < 3; ty++) {
        const float* ss = ssb + (size_t)ty * n * 4;
        const float* sd = sdb + (size_t)ty * n * 4;
        float4 svs = *(const float4*)&ss[s * 4];
        float4 svd = *(const float4*)&ss[d * 4];
        float4 dvd = *(const float4*)&sd[d * 4];
        float4 a;
        a.x = __expf(lrelu(svs.x + dvd.x) - lrelu(svd.x + dvd.x));
        a.y = __expf(lrelu(svs.y + dvd.y) - lrelu(svd.y + dvd.y));
        a.z = __expf(lrelu(svs.z + dvd.z) - lrelu(svd.z + dvd.z));
        a.w = __expf(lrelu(svs.w + dvd.w) - lrelu(svd.w + dvd.w));
        *(float4*)&al3[((size_t)ty * 2 * e + q) * 4] = a;
    }
}

// ============ pass B batched: wave per (type, node); al3 streamed by slot index (R21-proven) ============
__global__ void gat_fused_b(const unsigned short* __restrict__ xpO,
                            const unsigned short* __restrict__ xpS,
                            const float* __restrict__ al3,
                            const long long* __restrict__ cp2, const int* __restrict__ rp2,
                            const float* __restrict__ bgO, const float* __restrict__ bgS,
                            const float* __restrict__ embPart, const float* __restrict__ Wc,
                            const float* __restrict__ bc, float* __restrict__ out, int n) {
    const int wave = threadIdx.x >> 6, lane = threadIdx.x & 63;
    const int i3 = blockIdx.x * 4 + wave;
    if (i3 >= 3 * n) return;
    const int ty = i3 / n, i = i3 - ty * n;
    const int c = lane * 2, hh = lane >> 4;

    const unsigned short* xo = xpO + (size_t)ty * n * 128;
    const unsigned short* xs_ = xpS + (size_t)ty * n * 128;
    const float* alB = al3 + (size_t)ty * 2 * NEDGES * 4;   // indexed by absolute slot

    const int r0o = rp2[i], r1o = rp2[i + 1];
    const int r0s = rp2[n + i], r1s = rp2[n + i + 1];

    float tO = 0.f, oxO = 0.f, oyO = 0.f;
    float tS = 0.f, oxS = 0.f, oyS = 0.f;
    int ko = r0o, ks = r0s;

    // 4 independent load chains per iteration (2 O-edges + 2 S-edges); al reads stream with slot
    while (ko + 2 <= r1o && ks + 2 <= r1s) {
        long long vo0 = cp2[ko], vo1 = cp2[ko + 1];
        long long vs0 = cp2[ks], vs1 = cp2[ks + 1];
        int so0 = (int)(vo0 & 0xFFFFFFFFll), so1 = (int)(vo1 & 0xFFFFFFFFll);
        int sx0 = (int)(vs0 & 0xFFFFFFFFll), sx1 = (int)(vs1 & 0xFFFFFFFFll);
        float ao0 = alB[(size_t)ko * 4 + hh], ao1 = alB[(size_t)(ko + 1) * 4 + hh];
        float as0 = alB[(size_t)ks * 4 + hh], as1 = alB[(size_t)(ks + 1) * 4 + hh];
        unsigned uo0 = *(const unsigned*)&xo[(size_t)so0 * 128 + c];
        unsigned uo1 = *(const unsigned*)&xo[(size_t)so1 * 128 + c];
        unsigned us0 = *(const unsigned*)&xs_[(size_t)sx0 * 128 + c];
        unsigned us1 = *(const unsigned*)&xs_[(size_t)sx1 * 128 + c];
        tO += ao0 + ao1;
        oxO += ao0 * __uint_as_float(uo0 << 16) + ao1 * __uint_as_float(uo1 << 16);
        oyO += ao0 * __uint_as_float(uo0 & 0xFFFF0000u) + ao1 * __uint_as_float(uo1 & 0xFFFF0000u);
        tS += as0 + as1;
        oxS += as0 * __uint_as_float(us0 << 16) + as1 * __uint_as_float(us1 << 16);
        oyS += as0 * __uint_as_float(us0 & 0xFFFF0000u) + as1 * __uint_as_float(us1 & 0xFFFF0000u);
        ko += 2; ks += 2;
    }
    while (ko < r1o && ks < r1s) {
        long long vo = cp2[ko], vs = cp2[ks];
        int so = (int)(vo & 0xFFFFFFFFll), sx = (int)(vs & 0xFFFFFFFFll);
        float ao = alB[(size_t)ko * 4 + hh];
        float as_ = alB[(size_t)ks * 4 + hh];
        unsigned uo = *(const unsigned*)&xo[(size_t)so * 128 + c];
        unsigned us = *(const unsigned*)&xs_[(size_t)sx * 128 + c];
        tO += ao;
        oxO += ao * __uint_as_float(uo << 16);
        oyO += ao * __uint_as_float(uo & 0xFFFF0000u);
        tS += as_;
        oxS += as_ * __uint_as_float(us << 16);
        oyS += as_ * __uint_as_float(us & 0xFFFF0000u);
        ko++; ks++;
    }
    for (; ko + 2 <= r1o; ko += 2) {
        long long vo0 = cp2[ko], vo1 = cp2[ko + 1];
        int so0 = (int)(vo0 & 0xFFFFFFFFll), so1 = (int)(vo1 & 0xFFFFFFFFll);
        float ao0 = alB[(size_t)ko * 4 + hh], ao1 = alB[(size_t)(ko + 1) * 4 + hh];
        unsigned uo0 = *(const unsigned*)&xo[(size_t)so0 * 128 + c];
        unsigned uo1 = *(const unsigned*)&xo[(size_t)so1 * 128 + c];
        tO += ao0 + ao1;
        oxO += ao0 * __uint_as_float(uo0 << 16) + ao1 * __uint_as_float(uo1 << 16);
        oyO += ao0 * __uint_as_float(uo0 & 0xFFFF0000u) + ao1 * __uint_as_float(uo1 & 0xFFFF0000u);
    }
    for (; ko < r1o; ko++) {
        long long vo = cp2[ko];
        int so = (int)(vo & 0xFFFFFFFFll);
        float ao = alB[(size_t)ko * 4 + hh];
        unsigned uo = *(const unsigned*)&xo[(size_t)so * 128 + c];
        tO += ao;
        oxO += ao * __uint_as_float(uo << 16);
        oyO += ao * __uint_as_float(uo & 0xFFFF0000u);
    }
    for (; ks + 2 <= r1s; ks += 2) {
        long long vs0 = cp2[ks], vs1 = cp2[ks + 1];
        int sx0 = (int)(vs0 & 0xFFFFFFFFll), sx1 = (int)(vs1 & 0xFFFFFFFFll);
        float as0 = alB[(size_t)ks * 4 + hh], as1 = alB[(size_t)(ks + 1) * 4 + hh];
        unsigned us0 = *(const unsigned*)&xs_[(size_t)sx0 * 128 + c];
        unsigned us1 = *(const unsigned*)&xs_[(size_t)sx1 * 128 + c];
        tS += as0 + as1;
        oxS += as0 * __uint_as_float(us0 << 16) + as1 * __uint_as_float(us1 << 16);
        oyS += as0 * __uint_as_float(us0 & 0xFFFF0000u) + as1 * __uint_as_float(us1 & 0xFFFF0000u);
    }
    for (; ks < r1s; ks++) {
        long long vs = cp2[ks];
        int sx = (int)(vs & 0xFFFFFFFFll);
        float as_ = alB[(size_t)ks * 4 + hh];
        unsigned us = *(const unsigned*)&xs_[(size_t)sx * 128 + c];
        tS += as_;
        oxS += as_ * __uint_as_float(us << 16);
        oyS += as_ * __uint_as_float(us & 0xFFFF0000u);
    }
    {   // self-loops: raw alpha = exp(0) = 1
        unsigned uo = *(const unsigned*)&xo[(size_t)i * 128 + c];
        unsigned us = *(const unsigned*)&xs_[(size_t)i * 128 + c];
        oxO += __uint_as_float(uo << 16);
        oyO += __uint_as_float(uo & 0xFFFF0000u);
        oxS += __uint_as_float(us << 16);
        oyS += __uint_as_float(us & 0xFFFF0000u);
    }
    const float idO = 1.f / (tO + 1.f), idS = 1.f / (tS + 1.f);
    float fx = idO * oxO + idS * oxS + bgO[c] + bgS[c];
    float fy = idO * oyO + idS * oyS + bgO[c + 1] + bgS[c + 1];

    float2 w = *(const float2*)&Wc[c];
    float p = fx * w.x + fy * w.y;
#pragma unroll
    for (int o = 32; o > 0; o >>= 1) p += __shfl_xor(p, o);
    if (lane == 0) out[i3] = 1.f / (1.f + expf(-(p + embPart[i3] + bc[0])));
}

extern "C" void kernel_launch(void* const* d_in, const int* in_sizes, int n_in,
                              void* d_out, int out_size, void* d_ws, size_t ws_size,
                              hipStream_t stream) {
    const int N = NNODES, E = NEDGES;
    const float* x_acc = (const float*)d_in[0];
    const float* x_cus = (const float*)d_in[1];
    const float* x_txn = (const float*)d_in[2];
    const int* ei_owns = (const int*)d_in[4];
    const int* ei_shr = (const int*)d_in[5];
    const float* W_acc = (const float*)d_in[6];
    const float* b_acc = (const float*)d_in[7];
    const float* W_cus = (const float*)d_in[8];
    const float* b_cus = (const float*)d_in[9];
    const float* W_txn = (const float*)d_in[10];
    const float* b_txn = (const float*)d_in[11];
    const float* Wg_o = (const float*)d_in[12];
    const float* as_o = (const float*)d_in[13];
    const float* ad_o = (const float*)d_in[14];
    const float* bg_o = (const float*)d_in[15];
    const float* Wg_s = (const float*)d_in[16];
    const float* as_s = (const float*)d_in[17];
    const float* ad_s = (const float*)d_in[18];
    const float* bg_s = (const float*)d_in[19];
    const float* W_cls = (const float*)d_in[20];
    const float* b_cls = (const float*)d_in[21];
    float* out = (float*)d_out;

    float* wf = (float*)d_ws;
    int* iw = (int*)d_ws;
    // batched layout (all 3 types resident):
    unsigned short* xp_o3 = (unsigned short*)(wf + 0);          // 3N*128 bf16 = 9.6M f
    unsigned short* xp_s3 = (unsigned short*)(wf + 9600000);    // 9.6M f
    float* ss_o3 = wf + 19200000;                               // 3N*4 = 600k
    float* sd_o3 = wf + 19800000;
    float* ss_s3 = wf + 20400000;
    float* sd_s3 = wf + 21000000;
    float* al3   = wf + 21600000;                               // 3 * 2E * 4 = 12M (slot order)
    float* embPart = wf + 33600000;                             // 3N = 150k
    int* rp2    = iw + 33750008;                                // 2N+1
    long long* cp2 = (long long*)(iw + 33850016);               // 2E u64 (even int ofs)
    float* Wcomb = wf + 35850016;                               // 224*256 = 57344
    float* wc1   = wf + 35907360;                               // 224
    float* bcomb = wf + 35907584;                               // 3*256 = 768
    float* c0    = wf + 35908352;                               // 3
    // CSR scratch overlaps al3 region (dead until alpha_slot runs, after CSR completes):
    int* counts2 = (int*)al3;                                   // 2N
    int* cursor2 = counts2 + 100000;                            // 2N
    int* psum    = cursor2 + 100000;                            // 128

    const int gN2 = (2 * N + 255) / 256;
    const int gE2 = (2 * E + 255) / 256;
    const int gS2 = (2 * N + 1023) / 1024;  // 98 blocks
    const int gXP = 3 * NTILES;
    const int gA = (3 * N + 3) / 4;

    // prep: combined weights (fold embed GEMM into the xp GEMM)
    wprep_kernel<<<227, 256, 0, stream>>>(W_acc, W_cus, W_txn, b_acc, b_cus, b_txn,
                                          Wg_o, Wg_s, W_cls, Wcomb, wc1, bcomb, c0);

    // batched CSR for both edge types (src = row 0, dst = row 1); canonical slot order via sort
    zero_int<<<gN2, 256, 0, stream>>>(counts2, 2 * N);
    count2_kernel<<<gE2, 256, 0, stream>>>(ei_owns, ei_shr, E, N, counts2);
    block_sum_kernel<<<gS2, 1024, 0, stream>>>(counts2, 2 * N, psum);
    scan_psum_big<<<1, 128, 0, stream>>>(psum, gS2, rp2 + 2 * N);
    scan_block_kernel<<<gS2, 1024, 0, stream>>>(counts2, psum, 2 * N, rp2, cursor2);
    scatter2_kernel<<<gE2, 256, 0, stream>>>(ei_owns, ei_shr, E, N, cursor2, cp2);
    sort_rows_kernel<<<gN2, 256, 0, stream>>>(rp2, cp2, 2 * N);

    // batched: one xp launch -> one alpha launch (slot order) -> one aggregate launch
    xp_all_b<<<gXP, 256, 0, stream>>>(x_acc, x_cus, x_txn,
                                      Wcomb, wc1, bcomb, c0,
                                      as_o, ad_o, as_s, ad_s,
                                      embPart, xp_o3, xp_s3,
                                      ss_o3, sd_o3, ss_s3, sd_s3, N);
    alpha_slot_kernel<<<gE2, 256, 0, stream>>>(ei_owns, ei_shr, cp2,
                                               ss_o3, sd_o3, ss_s3, sd_s3,
                                               al3, E, N);
    gat_fused_b<<<gA, 256, 0, stream>>>(xp_o3, xp_s3, al3,
                                        cp2, rp2, bg_o, bg_s,
                                        embPart, W_cls, b_cls, out, N);
}